// Round 5
// baseline (246.405 us; speedup 1.0000x reference)
//
#include <hip/hip_runtime.h>
#include <hip/hip_bf16.h>

#define FEATSZ 2048
#define HIDSZ  1024
#define ATTSZ  512
#define BATCH  64
#define FEATN  512

typedef float  f32x4  __attribute__((ext_vector_type(4)));
typedef __bf16 bf16x8 __attribute__((ext_vector_type(8)));

__device__ __forceinline__ unsigned short f2bf(float f) {
    union { float f; unsigned int u; } x; x.f = f;
    unsigned int u = x.u;
    return (unsigned short)((u + 0x7fffu + ((u >> 16) & 1u)) >> 16);
}

// ---------------- K0a: h = key @ wh_w.T + wh_b  (64 x 512) ----------------
__global__ void k_h(const float* __restrict__ key, const float* __restrict__ wh_w,
                    const float* __restrict__ wh_b, float* __restrict__ h) {
    const int b = blockIdx.y;
    const int ac = blockIdx.x;
    const int t = threadIdx.x;         // 256
    const int lane = t & 63, wv = t >> 6;
    float k16[16];
    const float* kb = key + b * HIDSZ;
#pragma unroll
    for (int j = 0; j < 16; ++j) k16[j] = kb[lane + 64 * j];
#pragma unroll 1
    for (int i = 0; i < 16; ++i) {
        int a = ac * 64 + wv * 16 + i;
        const float* wr = wh_w + (size_t)a * HIDSZ;
        float s = 0.f;
#pragma unroll
        for (int j = 0; j < 16; ++j) s += k16[j] * wr[lane + 64 * j];
#pragma unroll
        for (int d = 32; d; d >>= 1) s += __shfl_xor(s, d);
        if (lane == 0) h[b * ATTSZ + a] = s + wh_b[a];
    }
}

// ------- K0b: convert wv_w (512x2048 f32) -> bf16 in MFMA-fragment order -------
// frag (kk, CF) occupies 1024B at (kk*32+CF)*1024; lane l holds 16B at +l*16.
__global__ void k_wvcvt(const float* __restrict__ wv_w, unsigned short* __restrict__ wvb) {
    int idx = blockIdx.x * 256 + threadIdx.x;       // < 512*2048
    int a = idx >> 11, k = idx & 2047;
    int CF = a >> 4, c = a & 15, ks = k >> 5, kin = k & 31;
    int lane = c + ((kin >> 3) << 4);
    int dst = ((ks * 32 + CF) * 64 + lane) * 8 + (kin & 7);
    wvb[dst] = f2bf(wv_w[idx]);
}

// ---------------- K1: fused GEMM(feats, wv^T) + tanh·wa -> scores ----------------
// Barrier-free: 256 blocks (1/CU), 8 free-running waves. Wave (wr=w>>2, wc=w&3)
// owns 64 rows x 128 cols. A fp32 DIRECT from global (frag = 2 dwordx4/lane,
// 4-slot rotation, 1-kk lookahead); B from relayout'd wvb (L2) ping-pong 1-kk
// ahead. No LDS in the K-loop; one barrier total (epilogue reduction).
__global__ __launch_bounds__(512, 2) void k_scores(
        const float* __restrict__ feats, const unsigned short* __restrict__ wvb,
        const float* __restrict__ h, const float* __restrict__ wv_b,
        const float* __restrict__ wa, float* __restrict__ scores) {
    __shared__ float scp[4][128];
    const int t = threadIdx.x, lane = t & 63, w = t >> 6;
    const int wr = w >> 2, wc = w & 3;
    const int m0 = blockIdx.x * 128, b = blockIdx.x >> 2;

    // A: lane reads row m0+wr*64+m*16+(lane&15), k = kk*32 + (lane>>4)*8 + [0..7]
    const float* ab = feats + (size_t)(m0 + wr * 64 + (lane & 15)) * FEATSZ + (lane >> 4) * 8;
    // B: frag (kk, wc*8+cf) at wvb + (kk*32 + wc*8 + cf)*512 + lane*8
    const unsigned short* wb = wvb + (wc * 8) * 512 + lane * 8;

    f32x4 acc[4][8];
#pragma unroll
    for (int m = 0; m < 4; ++m)
#pragma unroll
        for (int cf = 0; cf < 8; ++cf) acc[m][cf] = (f32x4)0.0f;

    f32x4 aA[4], aB[4];     // A slot m: k 0-3 / 4-7 (fp32)
    bf16x8 B[2][8];         // B ping-pong

    auto loadA = [&](int m, int kk, f32x4& x, f32x4& y) {
        const float* p = ab + (size_t)m * 16 * FEATSZ + kk * 32;
        x = *(const f32x4*)p;
        y = *(const f32x4*)(p + 4);
    };

    // prologue: A(kk=0) all 4 slots, B(kk=0) into parity 0
#pragma unroll
    for (int m = 0; m < 4; ++m) loadA(m, 0, aA[m], aB[m]);
#pragma unroll
    for (int cf = 0; cf < 8; ++cf) B[0][cf] = *(const bf16x8*)(wb + (0 * 32 + cf) * 512);

#pragma unroll 2
    for (int kk = 0; kk < 64; ++kk) {
        const int p = kk & 1;
        const int kn = kk < 63 ? kk + 1 : 63;
#pragma unroll
        for (int m = 0; m < 4; ++m) {
            bf16x8 af;
            af[0] = (__bf16)aA[m][0]; af[1] = (__bf16)aA[m][1];
            af[2] = (__bf16)aA[m][2]; af[3] = (__bf16)aA[m][3];
            af[4] = (__bf16)aB[m][0]; af[5] = (__bf16)aB[m][1];
            af[6] = (__bf16)aB[m][2]; af[7] = (__bf16)aB[m][3];
            loadA(m, kn, aA[m], aB[m]);                       // refill slot for kk+1
            if (m == 0) {
#pragma unroll
                for (int cf = 0; cf < 8; ++cf)                // B prefetch kk+1
                    B[p ^ 1][cf] = *(const bf16x8*)(wb + (kn * 32 + cf) * 512);
            }
            __builtin_amdgcn_s_setprio(1);
#pragma unroll
            for (int cf = 0; cf < 8; ++cf)
                acc[m][cf] = __builtin_amdgcn_mfma_f32_16x16x32_bf16(af, B[p][cf], acc[m][cf], 0, 0, 0);
            __builtin_amdgcn_s_setprio(0);
        }
    }

    // ---- epilogue: score[row] = sum_a tanh(v + h + wv_b) * wa
    const int c16 = lane & 15, q4 = lane >> 4;
    float hreg[8], wreg[8];
#pragma unroll
    for (int cf = 0; cf < 8; ++cf) {
        int a = wc * 128 + cf * 16 + c16;
        hreg[cf] = h[b * ATTSZ + a] + wv_b[a];
        wreg[cf] = wa[a];
    }
    float pv[4][4];
#pragma unroll
    for (int m = 0; m < 4; ++m)
#pragma unroll
        for (int j = 0; j < 4; ++j) pv[m][j] = 0.f;
#pragma unroll
    for (int m = 0; m < 4; ++m)
#pragma unroll
        for (int cf = 0; cf < 8; ++cf)
#pragma unroll
            for (int j = 0; j < 4; ++j)
                pv[m][j] += tanhf(acc[m][cf][j] + hreg[cf]) * wreg[cf];
#pragma unroll
    for (int m = 0; m < 4; ++m)
#pragma unroll
        for (int j = 0; j < 4; ++j) {
            float v = pv[m][j];
            v += __shfl_xor(v, 1); v += __shfl_xor(v, 2);
            v += __shfl_xor(v, 4); v += __shfl_xor(v, 8);
            pv[m][j] = v;
        }
    if (c16 == 0) {
#pragma unroll
        for (int m = 0; m < 4; ++m)
#pragma unroll
            for (int j = 0; j < 4; ++j)
                scp[wc][wr * 64 + m * 16 + q4 * 4 + j] = pv[m][j];
    }
    __syncthreads();
    if (t < 128) {
        float s = scp[0][t] + scp[1][t] + scp[2][t] + scp[3][t];
        scores[m0 + t] = s;
    }
}

// ---------------- K2: softmax over N=512 per batch ----------------
__global__ void k_softmax(const float* __restrict__ scores, float* __restrict__ alpha) {
    __shared__ float red[16];
    const int b = blockIdx.x, t = threadIdx.x;     // 512 threads
    const int lane = t & 63, w = t >> 6;
    float s = scores[b * FEATN + t];
    float m = s;
#pragma unroll
    for (int d = 32; d; d >>= 1) m = fmaxf(m, __shfl_xor(m, d));
    if (lane == 0) red[w] = m;
    __syncthreads();
    if (t == 0) {
        float mm = red[0];
        for (int i = 1; i < 8; ++i) mm = fmaxf(mm, red[i]);
        red[8] = mm;
    }
    __syncthreads();
    float e = __expf(s - red[8]);
    float sum = e;
#pragma unroll
    for (int d = 32; d; d >>= 1) sum += __shfl_xor(sum, d);
    if (lane == 0) red[w] = sum;
    __syncthreads();
    if (t == 0) {
        float ss = 0.f;
        for (int i = 0; i < 8; ++i) ss += red[i];
        red[9] = 1.0f / ss;
    }
    __syncthreads();
    alpha[b * FEATN + t] = e * red[9];
}

// ---------------- K3a: partial att_feats over n-slices ----------------
__global__ void k_att_part(const float* __restrict__ feats, const float* __restrict__ alpha,
                           float* __restrict__ part) {
    const int b = blockIdx.x, fc = blockIdx.y, ns = blockIdx.z, t = threadIdx.x;
    const int f0 = fc * 1024 + t * 4;
    const float* fp = feats + (size_t)(b * FEATN + ns * 128) * FEATSZ + f0;
    const float* al = alpha + b * FEATN + ns * 128;
    float4 acc = {0.f, 0.f, 0.f, 0.f};
#pragma unroll 4
    for (int i = 0; i < 128; ++i) {
        float a = al[i];
        float4 v = *(const float4*)(fp + (size_t)i * FEATSZ);
        acc.x += a * v.x; acc.y += a * v.y; acc.z += a * v.z; acc.w += a * v.w;
    }
    *(float4*)(part + ((size_t)ns * BATCH + b) * FEATSZ + f0) = acc;
}

// ---------------- K3b: reduce 4 partials -> att_feats ----------------
__global__ void k_att_red(const float* __restrict__ part, float* __restrict__ out) {
    const int idx = (blockIdx.x * 256 + threadIdx.x) * 4;   // < 131072
    float4 s = *(const float4*)(part + idx);
#pragma unroll
    for (int z = 1; z < 4; ++z) {
        float4 v = *(const float4*)(part + (size_t)z * (BATCH * FEATSZ) + idx);
        s.x += v.x; s.y += v.y; s.z += v.z; s.w += v.w;
    }
    *(float4*)(out + idx) = s;
}

extern "C" void kernel_launch(void* const* d_in, const int* in_sizes, int n_in,
                              void* d_out, int out_size, void* d_ws, size_t ws_size,
                              hipStream_t stream) {
    const float* feats = (const float*)d_in[0];
    const float* key   = (const float*)d_in[1];
    const float* wh_w  = (const float*)d_in[2];
    const float* wh_b  = (const float*)d_in[3];
    const float* wv_w  = (const float*)d_in[4];
    const float* wv_b  = (const float*)d_in[5];
    const float* wa_w  = (const float*)d_in[6];

    float* out_att   = (float*)d_out;                 // 64*2048
    float* out_alpha = out_att + BATCH * FEATSZ;      // 64*512

    char* ws = (char*)d_ws;
    float* h              = (float*)(ws);             // 128 KB
    float* scores         = (float*)(ws + 131072);    // 128 KB
    unsigned short* wvb   = (unsigned short*)(ws + 262144);  // 2 MB (used by K0b/K1)
    float* part           = (float*)(ws + 262144);    // 2 MB (reuses wvb region after K1)

    hipLaunchKernelGGL(k_h,        dim3(8, 64),    dim3(256), 0, stream, key, wh_w, wh_b, h);
    hipLaunchKernelGGL(k_wvcvt,    dim3(4096),     dim3(256), 0, stream, wv_w, wvb);
    hipLaunchKernelGGL(k_scores,   dim3(256),      dim3(512), 0, stream, feats, wvb, h, wv_b, wa_w, scores);
    hipLaunchKernelGGL(k_softmax,  dim3(64),       dim3(512), 0, stream, scores, out_alpha);
    hipLaunchKernelGGL(k_att_part, dim3(64, 2, 4), dim3(256), 0, stream, feats, out_alpha, part);
    hipLaunchKernelGGL(k_att_red,  dim3(128),      dim3(256), 0, stream, part, out_att);
}